// Round 5
// baseline (252.134 us; speedup 1.0000x reference)
//
#include <hip/hip_runtime.h>
#include <math.h>

#define BATCH 32
#define NSAMP 262144
#define NKNOT 256
#define EPSV  0.001f
#define CH    16                  // samples per chunk (per thread)
#define CPB   256                 // chunks per block (= threads)
#define SPB   (CH * CPB)          // 4096 samples per block
#define NCROW (NSAMP / CH)        // 16384 chunks per row
#define BPR   (NCROW / CPB)       // 64 blocks per row
#define NB    (BATCH * BPR)       // 2048 blocks total (exactly 8/CU)

#define SCOPE_AGENT __HIP_MEMORY_SCOPE_AGENT

__device__ __forceinline__ float fast_tanh(float x) {
    // tanh(x) = 1 - 2/(exp(2x)+1); branch-free, ~1e-7 abs error
    float e = __expf(2.0f * x);
    float r = __builtin_amdgcn_rcpf(e + 1.0f);
    return fmaf(-2.0f, r, 1.0f);
}

// tile is [CPB][CH] with an XOR swizzle on 4-word groups so that both the
// per-thread row reads (b128) and the block-linear writes spread start-banks
// like the canonical consecutive layout. Same involution on write AND read.
__device__ __forceinline__ float* tptr(float* t, int cc, int j4) {
    return t + cc * CH + (j4 ^ ((cc & 3) << 2));
}

__global__ __launch_bounds__(256, 8) void k_fused(
    const float* __restrict__ x,
    const float* __restrict__ cl,       // [BATCH][NKNOT][5]
    float* __restrict__ aggD,           // [NB][6] block-aggregate affine maps
    unsigned int* __restrict__ flags,   // [NB] publish flags (zeroed per call)
    float* __restrict__ out)
{
    __shared__ float tile[CPB * CH];    // 16 KB
    __shared__ float wag[4][6];
    __shared__ float sInit[2];
    const int tid = threadIdx.x;
    const int b = blockIdx.x;
    const int lane = tid & 63, wid = tid >> 6;

    // ---- Phase 0: coalesced global load -> swizzled LDS tile ----
    const float4* x4 = (const float4*)x + (size_t)b * (SPB / 4);
    #pragma unroll
    for (int i = 0; i < SPB / 4 / 256; ++i) {       // 4 iters
        int ii = tid + i * 256;
        float4 v = x4[ii];
        *(float4*)tptr(tile, ii >> 2, (ii & 3) << 2) = v;
    }

    // ---- knot coefficients for this thread's chunk (<=2 segments) ----
    int chunk = b * CPB + tid;
    int r = chunk >> 14;                 // / NCROW (16384 = 2^14)
    int c = chunk & (NCROW - 1);
    const float scale = 255.0f / 262143.0f;
    int t0 = c * CH;
    float pos0 = (float)t0 * scale;
    float fiA = floorf(pos0);
    int idxA = (int)fiA;
    float w0v = pos0 - fiA;
    const float* kb = cl + (size_t)r * NKNOT * 5;
    int i0 = idxA;
    int i1 = min(idxA + 1, NKNOT - 1);
    int i2 = min(idxA + 2, NKNOT - 1);
    float k00 = kb[i0*5+0], k01 = kb[i1*5+0], k02 = kb[i2*5+0];
    float k10 = kb[i0*5+1], k11 = kb[i1*5+1], k12 = kb[i2*5+1];
    float k20 = kb[i0*5+2], k21 = kb[i1*5+2], k22 = kb[i2*5+2];
    float k30 = kb[i0*5+3], k31 = kb[i1*5+3], k32 = kb[i2*5+3];
    float k40 = kb[i0*5+4], k41 = kb[i1*5+4], k42 = kb[i2*5+4];

    __syncthreads();

    // ---- Phase 1: build per-chunk affine map s_end = M s_start + v ----
    const float stab = 1.0f - EPSV, stab2 = 2.0f * stab;
    float p1 = 0.f, p2 = 0.f;          // particular (zero init)
    float A1 = 1.f, A2 = 0.f;          // homogeneous resp to (1,0)
    float B1 = 0.f, B2 = 1.f;          // homogeneous resp to (0,1)
    #pragma unroll
    for (int jj = 0; jj < CH / 4; ++jj) {
        float4 xq = *(const float4*)tptr(tile, tid, jj << 2);
        #pragma unroll
        for (int q = 0; q < 4; ++q) {
            float xs = (&xq.x)[q];
            float w = fmaf((float)(jj * 4 + q), scale, w0v);
            bool sel = w >= 1.0f;
            float wu = sel ? w - 1.0f : w;
            float l0a = sel ? k01 : k00, l0b = sel ? k02 : k01;
            float l1a = sel ? k11 : k10, l1b = sel ? k12 : k11;
            float l0 = fmaf(wu, l0b - l0a, l0a);
            float l1 = fmaf(wu, l1b - l1a, l1a);
            float a1 = stab2 * fast_tanh(l0);
            float a1a = fabsf(a1);
            float a2 = 0.5f * fmaf((2.0f - a1a) * stab, fast_tanh(l1), a1a);
            float p  = fmaf(-a2, p2, xs);  p = fmaf(-a1, p1, p);
            float hA = fmaf(-a1, A1, -a2 * A2);
            float hB = fmaf(-a1, B1, -a2 * B2);
            p2 = p1; p1 = p;
            A2 = A1; A1 = hA;
            B2 = B1; B1 = hB;
        }
    }
    float L00 = A1, L01 = B1, L10 = A2, L11 = B2, Lv0 = p1, Lv1 = p2;

    // ---- Phase 2: intra-block affine scan (wave shfl + cross-wave LDS) ----
    #pragma unroll
    for (int d = 1; d < 64; d <<= 1) {
        float o00 = __shfl_up(L00, d), o01 = __shfl_up(L01, d);
        float o10 = __shfl_up(L10, d), o11 = __shfl_up(L11, d);
        float ov0 = __shfl_up(Lv0, d), ov1 = __shfl_up(Lv1, d);
        if (lane >= d) {
            float n00 = L00 * o00 + L01 * o10;
            float n01 = L00 * o01 + L01 * o11;
            float n10 = L10 * o00 + L11 * o10;
            float n11 = L10 * o01 + L11 * o11;
            float nv0 = fmaf(L00, ov0, fmaf(L01, ov1, Lv0));
            float nv1 = fmaf(L10, ov0, fmaf(L11, ov1, Lv1));
            L00 = n00; L01 = n01; L10 = n10; L11 = n11; Lv0 = nv0; Lv1 = nv1;
        }
    }
    if (lane == 63) {
        wag[wid][0] = L00; wag[wid][1] = L01; wag[wid][2] = L10;
        wag[wid][3] = L11; wag[wid][4] = Lv0; wag[wid][5] = Lv1;
    }
    __syncthreads();
    // P = compose of earlier waves' aggregates
    float P00 = 1.f, P01 = 0.f, P10 = 0.f, P11 = 1.f, Pv0 = 0.f, Pv1 = 0.f;
    for (int w2 = 0; w2 < wid; ++w2) {
        float a00 = wag[w2][0], a01 = wag[w2][1], a10 = wag[w2][2];
        float a11 = wag[w2][3], av0 = wag[w2][4], av1 = wag[w2][5];
        float n00 = a00 * P00 + a01 * P10;
        float n01 = a00 * P01 + a01 * P11;
        float n10 = a10 * P00 + a11 * P10;
        float n11 = a10 * P01 + a11 * P11;
        float nv0 = fmaf(a00, Pv0, fmaf(a01, Pv1, av0));
        float nv1 = fmaf(a10, Pv0, fmaf(a11, Pv1, av1));
        P00 = n00; P01 = n01; P10 = n10; P11 = n11; Pv0 = nv0; Pv1 = nv1;
    }
    // in-wave exclusive E
    float E00 = __shfl_up(L00, 1), E01 = __shfl_up(L01, 1);
    float E10 = __shfl_up(L10, 1), E11 = __shfl_up(L11, 1);
    float Ev0 = __shfl_up(Lv0, 1), Ev1 = __shfl_up(Lv1, 1);
    if (lane == 0) { E00 = 1.f; E01 = 0.f; E10 = 0.f; E11 = 1.f; Ev0 = 0.f; Ev1 = 0.f; }
    // C = E ∘ P : exclusive prefix from block start to this thread's chunk
    float C00 = E00 * P00 + E01 * P10;
    float C01 = E00 * P01 + E01 * P11;
    float C10 = E10 * P00 + E11 * P10;
    float C11 = E10 * P01 + E11 * P11;
    float Cv0 = fmaf(E00, Pv0, fmaf(E01, Pv1, Ev0));
    float Cv1 = fmaf(E10, Pv0, fmaf(E11, Pv1, Ev1));

    // ---- publish block aggregate G = L(tid=255) ∘ P (release flag) ----
    if (tid == 255) {
        float G00 = L00 * P00 + L01 * P10;
        float G01 = L00 * P01 + L01 * P11;
        float G10 = L10 * P00 + L11 * P10;
        float G11 = L10 * P01 + L11 * P11;
        float Gv0 = fmaf(L00, Pv0, fmaf(L01, Pv1, Lv0));
        float Gv1 = fmaf(L10, Pv0, fmaf(L11, Pv1, Lv1));
        __hip_atomic_store(&aggD[b*6+0], G00, __ATOMIC_RELAXED, SCOPE_AGENT);
        __hip_atomic_store(&aggD[b*6+1], G01, __ATOMIC_RELAXED, SCOPE_AGENT);
        __hip_atomic_store(&aggD[b*6+2], G10, __ATOMIC_RELAXED, SCOPE_AGENT);
        __hip_atomic_store(&aggD[b*6+3], G11, __ATOMIC_RELAXED, SCOPE_AGENT);
        __hip_atomic_store(&aggD[b*6+4], Gv0, __ATOMIC_RELAXED, SCOPE_AGENT);
        __hip_atomic_store(&aggD[b*6+5], Gv1, __ATOMIC_RELAXED, SCOPE_AGENT);
        __hip_atomic_store(&flags[b], 1u, __ATOMIC_RELEASE, SCOPE_AGENT);
    }

    // ---- Phase 3: decoupled lookback (wave 0, one lane per predecessor) ----
    const int myIdx = b & (BPR - 1);
    const int rowFirst = b - myIdx;
    if (wid == 0) {
        float A00 = 1.f, A01 = 0.f, A10 = 0.f, A11 = 1.f, Av0 = 0.f, Av1 = 0.f;
        if (lane < myIdx) {
            int k = rowFirst + lane;
            while (__hip_atomic_load(&flags[k], __ATOMIC_ACQUIRE, SCOPE_AGENT) == 0u)
                __builtin_amdgcn_s_sleep(4);
            A00 = __hip_atomic_load(&aggD[k*6+0], __ATOMIC_RELAXED, SCOPE_AGENT);
            A01 = __hip_atomic_load(&aggD[k*6+1], __ATOMIC_RELAXED, SCOPE_AGENT);
            A10 = __hip_atomic_load(&aggD[k*6+2], __ATOMIC_RELAXED, SCOPE_AGENT);
            A11 = __hip_atomic_load(&aggD[k*6+3], __ATOMIC_RELAXED, SCOPE_AGENT);
            Av0 = __hip_atomic_load(&aggD[k*6+4], __ATOMIC_RELAXED, SCOPE_AGENT);
            Av1 = __hip_atomic_load(&aggD[k*6+5], __ATOMIC_RELAXED, SCOPE_AGENT);
        }
        // inclusive shfl scan compose (later ∘ earlier) over 64 lanes
        #pragma unroll
        for (int d = 1; d < 64; d <<= 1) {
            float o00 = __shfl_up(A00, d), o01 = __shfl_up(A01, d);
            float o10 = __shfl_up(A10, d), o11 = __shfl_up(A11, d);
            float ov0 = __shfl_up(Av0, d), ov1 = __shfl_up(Av1, d);
            if (lane >= d) {
                float n00 = A00 * o00 + A01 * o10;
                float n01 = A00 * o01 + A01 * o11;
                float n10 = A10 * o00 + A11 * o10;
                float n11 = A10 * o01 + A11 * o11;
                float nv0 = fmaf(A00, ov0, fmaf(A01, ov1, Av0));
                float nv1 = fmaf(A10, ov0, fmaf(A11, ov1, Av1));
                A00 = n00; A01 = n01; A10 = n10; A11 = n11; Av0 = nv0; Av1 = nv1;
            }
        }
        // predecessors' compose applied to zero row-init = vector at lane myIdx-1
        float s0 = 0.f, s1 = 0.f;
        if (myIdx > 0) {
            s0 = __shfl(Av0, myIdx - 1);
            s1 = __shfl(Av1, myIdx - 1);
        }
        if (lane == 0) { sInit[0] = s0; sInit[1] = s1; }
    }
    __syncthreads();
    float s0 = sInit[0], s1 = sInit[1];

    // this thread's chunk initial state (y[t0-1], y[t0-2])
    float y1 = fmaf(C00, s0, fmaf(C01, s1, Cv0));
    float y2 = fmaf(C10, s0, fmaf(C11, s1, Cv1));

    // ---- Phase 4: apply recurrence + fused FIR, write y back into tile ----
    #pragma unroll
    for (int jj = 0; jj < CH / 4; ++jj) {
        float* tp = tptr(tile, tid, jj << 2);
        float4 xq = *(const float4*)tp;
        float4 ov;
        #pragma unroll
        for (int q = 0; q < 4; ++q) {
            float xs = (&xq.x)[q];
            float w = fmaf((float)(jj * 4 + q), scale, w0v);
            bool sel = w >= 1.0f;
            float wu = sel ? w - 1.0f : w;
            float l0a = sel ? k01 : k00, l0b = sel ? k02 : k01;
            float l1a = sel ? k11 : k10, l1b = sel ? k12 : k11;
            float b0a = sel ? k21 : k20, b0b = sel ? k22 : k21;
            float b1a = sel ? k31 : k30, b1b = sel ? k32 : k31;
            float b2a = sel ? k41 : k40, b2b = sel ? k42 : k41;
            float l0 = fmaf(wu, l0b - l0a, l0a);
            float l1 = fmaf(wu, l1b - l1a, l1a);
            float b0 = fmaf(wu, b0b - b0a, b0a);
            float b1 = fmaf(wu, b1b - b1a, b1a);
            float b2 = fmaf(wu, b2b - b2a, b2a);
            float a1 = stab2 * fast_tanh(l0);
            float a1a = fabsf(a1);
            float a2 = 0.5f * fmaf((2.0f - a1a) * stab, fast_tanh(l1), a1a);
            float y = fmaf(-a2, y2, xs);  y = fmaf(-a1, y1, y);
            (&ov.x)[q] = fmaf(b0, y, fmaf(b1, y1, b2 * y2));
            y2 = y1; y1 = y;
        }
        *(float4*)tp = ov;
    }
    __syncthreads();

    // ---- Phase 5: coalesced float4 store ----
    float4* out4 = (float4*)out + (size_t)b * (SPB / 4);
    #pragma unroll
    for (int i = 0; i < SPB / 4 / 256; ++i) {
        int ii = tid + i * 256;
        out4[ii] = *(const float4*)tptr(tile, ii >> 2, (ii & 3) << 2);
    }
}

extern "C" void kernel_launch(void* const* d_in, const int* in_sizes, int n_in,
                              void* d_out, int out_size, void* d_ws, size_t ws_size,
                              hipStream_t stream) {
    const float* x  = (const float*)d_in[0];   // [32][262144]
    const float* cl = (const float*)d_in[1];   // [32][256][5]
    float* out = (float*)d_out;
    float* aggD = (float*)d_ws;                       // NB*6 floats
    unsigned int* flags = (unsigned int*)(aggD + (size_t)NB * 6);  // NB uints

    // reset publish flags each call (graph-capturable memset node)
    hipMemsetAsync(flags, 0, NB * sizeof(unsigned int), stream);

    hipLaunchKernelGGL(k_fused, dim3(NB), dim3(256), 0, stream,
                       x, cl, aggD, flags, out);
}

// Round 6
// 83.045 us; speedup vs baseline: 3.0361x; 3.0361x over previous
//
#include <hip/hip_runtime.h>
#include <math.h>

#define BATCH 32
#define NSAMP 262144
#define NKNOT 256
#define EPSV  0.001f
#define CH    16                  // samples per chunk (per thread)
#define CPB   512                 // chunks per block (= threads/block)
#define SPB   (CH * CPB)          // 8192 samples per block
#define NCROW (NSAMP / CH)        // 16384 chunks per row
#define BPR   (NCROW / CPB)       // 32 blocks per row
#define NB    (BATCH * BPR)       // 1024 blocks
#define NWAVE (CPB / 64)          // 8 waves per block

__device__ __forceinline__ float fast_tanh(float x) {
    // tanh(x) = 1 - 2/(exp(2x)+1); branch-free, ~1e-7 abs error
    float e = __expf(2.0f * x);
    float r = __builtin_amdgcn_rcpf(e + 1.0f);
    return fmaf(-2.0f, r, 1.0f);
}

// ---------------------------------------------------------------------------
// Kernel 1: per-block aggregate affine map G[b] (no atomics, 24 KB output)
// ---------------------------------------------------------------------------
__global__ __launch_bounds__(512, 8) void k_agg(
    const float* __restrict__ x,
    const float* __restrict__ cl,     // [BATCH][NKNOT][5]
    float* __restrict__ G)            // [NB][6]
{
    __shared__ float tile[CH][CPB + 1];   // transposed, conflict-free (r4: 0 conflicts)
    __shared__ float wag[NWAVE][6];
    const int tid = threadIdx.x;
    const int b = blockIdx.x;
    const int lane = tid & 63, wid = tid >> 6;

    // coalesced global load -> transposed LDS
    const float4* x4 = (const float4*)x + (size_t)b * (SPB / 4);
    #pragma unroll
    for (int i = 0; i < SPB / 4 / CPB; ++i) {   // 4 iters
        int ii = tid + i * CPB;
        float4 v = x4[ii];
        int idx = ii << 2;
        int cc = idx >> 4, qq = idx & 15;
        tile[qq + 0][cc] = v.x;
        tile[qq + 1][cc] = v.y;
        tile[qq + 2][cc] = v.z;
        tile[qq + 3][cc] = v.w;
    }

    // knot coefficients (channels 0,1) for this thread's chunk
    int chunk = b * CPB + tid;
    int r = chunk >> 14;                 // / NCROW (16384)
    int c = chunk & (NCROW - 1);
    const float scale = 255.0f / 262143.0f;
    float pos0 = (float)(c * CH) * scale;
    float fiA = floorf(pos0);
    int idxA = (int)fiA;
    float w0v = pos0 - fiA;
    const float* kb = cl + (size_t)r * NKNOT * 5;
    int i1 = min(idxA + 1, NKNOT - 1);
    int i2 = min(idxA + 2, NKNOT - 1);
    float k00 = kb[idxA*5+0], k01 = kb[i1*5+0], k02 = kb[i2*5+0];
    float k10 = kb[idxA*5+1], k11 = kb[i1*5+1], k12 = kb[i2*5+1];

    __syncthreads();

    // build per-chunk affine map
    const float stab = 1.0f - EPSV, stab2 = 2.0f * stab;
    float p1 = 0.f, p2 = 0.f, A1 = 1.f, A2 = 0.f, B1 = 0.f, B2 = 1.f;
    #pragma unroll
    for (int j = 0; j < CH; ++j) {
        float xs = tile[j][tid];
        float w = fmaf((float)j, scale, w0v);
        bool sel = w >= 1.0f;
        float wu = sel ? w - 1.0f : w;
        float l0a = sel ? k01 : k00, l0b = sel ? k02 : k01;
        float l1a = sel ? k11 : k10, l1b = sel ? k12 : k11;
        float l0 = fmaf(wu, l0b - l0a, l0a);
        float l1 = fmaf(wu, l1b - l1a, l1a);
        float a1 = stab2 * fast_tanh(l0);
        float a1a = fabsf(a1);
        float a2 = 0.5f * fmaf((2.0f - a1a) * stab, fast_tanh(l1), a1a);
        float p  = fmaf(-a2, p2, xs);  p = fmaf(-a1, p1, p);
        float hA = fmaf(-a1, A1, -a2 * A2);
        float hB = fmaf(-a1, B1, -a2 * B2);
        p2 = p1; p1 = p;
        A2 = A1; A1 = hA;
        B2 = B1; B1 = hB;
    }
    float L00 = A1, L01 = B1, L10 = A2, L11 = B2, Lv0 = p1, Lv1 = p2;

    // wave-inclusive scan
    #pragma unroll
    for (int d = 1; d < 64; d <<= 1) {
        float o00 = __shfl_up(L00, d), o01 = __shfl_up(L01, d);
        float o10 = __shfl_up(L10, d), o11 = __shfl_up(L11, d);
        float ov0 = __shfl_up(Lv0, d), ov1 = __shfl_up(Lv1, d);
        if (lane >= d) {
            float n00 = L00 * o00 + L01 * o10;
            float n01 = L00 * o01 + L01 * o11;
            float n10 = L10 * o00 + L11 * o10;
            float n11 = L10 * o01 + L11 * o11;
            float nv0 = fmaf(L00, ov0, fmaf(L01, ov1, Lv0));
            float nv1 = fmaf(L10, ov0, fmaf(L11, ov1, Lv1));
            L00 = n00; L01 = n01; L10 = n10; L11 = n11; Lv0 = nv0; Lv1 = nv1;
        }
    }
    if (lane == 63) {
        wag[wid][0] = L00; wag[wid][1] = L01; wag[wid][2] = L10;
        wag[wid][3] = L11; wag[wid][4] = Lv0; wag[wid][5] = Lv1;
    }
    __syncthreads();

    // last thread composes all wave aggregates -> block aggregate
    if (tid == CPB - 1) {
        float P00 = 1.f, P01 = 0.f, P10 = 0.f, P11 = 1.f, Pv0 = 0.f, Pv1 = 0.f;
        for (int w2 = 0; w2 < NWAVE - 1; ++w2) {
            float a00 = wag[w2][0], a01 = wag[w2][1], a10 = wag[w2][2];
            float a11 = wag[w2][3], av0 = wag[w2][4], av1 = wag[w2][5];
            float n00 = a00 * P00 + a01 * P10;
            float n01 = a00 * P01 + a01 * P11;
            float n10 = a10 * P00 + a11 * P10;
            float n11 = a10 * P01 + a11 * P11;
            float nv0 = fmaf(a00, Pv0, fmaf(a01, Pv1, av0));
            float nv1 = fmaf(a10, Pv0, fmaf(a11, Pv1, av1));
            P00 = n00; P01 = n01; P10 = n10; P11 = n11; Pv0 = nv0; Pv1 = nv1;
        }
        G[b*6+0] = L00 * P00 + L01 * P10;
        G[b*6+1] = L00 * P01 + L01 * P11;
        G[b*6+2] = L10 * P00 + L11 * P10;
        G[b*6+3] = L10 * P01 + L11 * P11;
        G[b*6+4] = fmaf(L00, Pv0, fmaf(L01, Pv1, Lv0));
        G[b*6+5] = fmaf(L10, Pv0, fmaf(L11, Pv1, Lv1));
    }
}

// ---------------------------------------------------------------------------
// Kernel 2: per-row scan of 32 block aggregates -> block-start states
// ---------------------------------------------------------------------------
__global__ __launch_bounds__(64) void k_rowscan(
    const float* __restrict__ G,      // [NB][6]
    float* __restrict__ S)            // [NB][2] block-start states
{
    int r = blockIdx.x;               // row
    int lane = threadIdx.x;           // 64 (only BPR=32 active)
    int rowFirst = r * BPR;
    float A00 = 1.f, A01 = 0.f, A10 = 0.f, A11 = 1.f, Av0 = 0.f, Av1 = 0.f;
    if (lane < BPR) {
        int k = rowFirst + lane;
        A00 = G[k*6+0]; A01 = G[k*6+1]; A10 = G[k*6+2];
        A11 = G[k*6+3]; Av0 = G[k*6+4]; Av1 = G[k*6+5];
    }
    #pragma unroll
    for (int d = 1; d < BPR; d <<= 1) {
        float o00 = __shfl_up(A00, d), o01 = __shfl_up(A01, d);
        float o10 = __shfl_up(A10, d), o11 = __shfl_up(A11, d);
        float ov0 = __shfl_up(Av0, d), ov1 = __shfl_up(Av1, d);
        if (lane >= d) {
            float n00 = A00 * o00 + A01 * o10;
            float n01 = A00 * o01 + A01 * o11;
            float n10 = A10 * o00 + A11 * o10;
            float n11 = A10 * o01 + A11 * o11;
            float nv0 = fmaf(A00, ov0, fmaf(A01, ov1, Av0));
            float nv1 = fmaf(A10, ov0, fmaf(A11, ov1, Av1));
            A00 = n00; A01 = n01; A10 = n10; A11 = n11; Av0 = nv0; Av1 = nv1;
        }
    }
    // exclusive: state entering block (zero row-init -> vector part only)
    float e0 = __shfl_up(Av0, 1);
    float e1 = __shfl_up(Av1, 1);
    if (lane == 0) { e0 = 0.f; e1 = 0.f; }
    if (lane < BPR) {
        S[(rowFirst + lane)*2 + 0] = e0;
        S[(rowFirst + lane)*2 + 1] = e1;
    }
}

// ---------------------------------------------------------------------------
// Kernel 3: rebuild + intra-block scan + apply recurrence + fused FIR
// ---------------------------------------------------------------------------
__global__ __launch_bounds__(512, 8) void k_apply(
    const float* __restrict__ x,
    const float* __restrict__ cl,
    const float* __restrict__ S,      // [NB][2]
    float* __restrict__ out)
{
    __shared__ float tile[CH][CPB + 1];
    __shared__ float wag[NWAVE][6];
    const int tid = threadIdx.x;
    const int b = blockIdx.x;
    const int lane = tid & 63, wid = tid >> 6;

    const float4* x4 = (const float4*)x + (size_t)b * (SPB / 4);
    #pragma unroll
    for (int i = 0; i < SPB / 4 / CPB; ++i) {
        int ii = tid + i * CPB;
        float4 v = x4[ii];
        int idx = ii << 2;
        int cc = idx >> 4, qq = idx & 15;
        tile[qq + 0][cc] = v.x;
        tile[qq + 1][cc] = v.y;
        tile[qq + 2][cc] = v.z;
        tile[qq + 3][cc] = v.w;
    }

    int chunk = b * CPB + tid;
    int r = chunk >> 14;
    int c = chunk & (NCROW - 1);
    const float scale = 255.0f / 262143.0f;
    float pos0 = (float)(c * CH) * scale;
    float fiA = floorf(pos0);
    int idxA = (int)fiA;
    float w0v = pos0 - fiA;
    const float* kb = cl + (size_t)r * NKNOT * 5;
    int i1 = min(idxA + 1, NKNOT - 1);
    int i2 = min(idxA + 2, NKNOT - 1);
    float k00 = kb[idxA*5+0], k01 = kb[i1*5+0], k02 = kb[i2*5+0];
    float k10 = kb[idxA*5+1], k11 = kb[i1*5+1], k12 = kb[i2*5+1];
    float k20 = kb[idxA*5+2], k21 = kb[i1*5+2], k22 = kb[i2*5+2];
    float k30 = kb[idxA*5+3], k31 = kb[i1*5+3], k32 = kb[i2*5+3];
    float k40 = kb[idxA*5+4], k41 = kb[i1*5+4], k42 = kb[i2*5+4];

    __syncthreads();

    // rebuild per-chunk affine map (channels 0,1 only)
    const float stab = 1.0f - EPSV, stab2 = 2.0f * stab;
    float p1 = 0.f, p2 = 0.f, A1 = 1.f, A2 = 0.f, B1 = 0.f, B2 = 1.f;
    #pragma unroll
    for (int j = 0; j < CH; ++j) {
        float xs = tile[j][tid];
        float w = fmaf((float)j, scale, w0v);
        bool sel = w >= 1.0f;
        float wu = sel ? w - 1.0f : w;
        float l0a = sel ? k01 : k00, l0b = sel ? k02 : k01;
        float l1a = sel ? k11 : k10, l1b = sel ? k12 : k11;
        float l0 = fmaf(wu, l0b - l0a, l0a);
        float l1 = fmaf(wu, l1b - l1a, l1a);
        float a1 = stab2 * fast_tanh(l0);
        float a1a = fabsf(a1);
        float a2 = 0.5f * fmaf((2.0f - a1a) * stab, fast_tanh(l1), a1a);
        float p  = fmaf(-a2, p2, xs);  p = fmaf(-a1, p1, p);
        float hA = fmaf(-a1, A1, -a2 * A2);
        float hB = fmaf(-a1, B1, -a2 * B2);
        p2 = p1; p1 = p;
        A2 = A1; A1 = hA;
        B2 = B1; B1 = hB;
    }
    float L00 = A1, L01 = B1, L10 = A2, L11 = B2, Lv0 = p1, Lv1 = p2;

    // wave-inclusive scan
    #pragma unroll
    for (int d = 1; d < 64; d <<= 1) {
        float o00 = __shfl_up(L00, d), o01 = __shfl_up(L01, d);
        float o10 = __shfl_up(L10, d), o11 = __shfl_up(L11, d);
        float ov0 = __shfl_up(Lv0, d), ov1 = __shfl_up(Lv1, d);
        if (lane >= d) {
            float n00 = L00 * o00 + L01 * o10;
            float n01 = L00 * o01 + L01 * o11;
            float n10 = L10 * o00 + L11 * o10;
            float n11 = L10 * o01 + L11 * o11;
            float nv0 = fmaf(L00, ov0, fmaf(L01, ov1, Lv0));
            float nv1 = fmaf(L10, ov0, fmaf(L11, ov1, Lv1));
            L00 = n00; L01 = n01; L10 = n10; L11 = n11; Lv0 = nv0; Lv1 = nv1;
        }
    }
    if (lane == 63) {
        wag[wid][0] = L00; wag[wid][1] = L01; wag[wid][2] = L10;
        wag[wid][3] = L11; wag[wid][4] = Lv0; wag[wid][5] = Lv1;
    }
    __syncthreads();
    // P = compose of earlier waves
    float P00 = 1.f, P01 = 0.f, P10 = 0.f, P11 = 1.f, Pv0 = 0.f, Pv1 = 0.f;
    for (int w2 = 0; w2 < wid; ++w2) {
        float a00 = wag[w2][0], a01 = wag[w2][1], a10 = wag[w2][2];
        float a11 = wag[w2][3], av0 = wag[w2][4], av1 = wag[w2][5];
        float n00 = a00 * P00 + a01 * P10;
        float n01 = a00 * P01 + a01 * P11;
        float n10 = a10 * P00 + a11 * P10;
        float n11 = a10 * P01 + a11 * P11;
        float nv0 = fmaf(a00, Pv0, fmaf(a01, Pv1, av0));
        float nv1 = fmaf(a10, Pv0, fmaf(a11, Pv1, av1));
        P00 = n00; P01 = n01; P10 = n10; P11 = n11; Pv0 = nv0; Pv1 = nv1;
    }
    // in-wave exclusive E
    float E00 = __shfl_up(L00, 1), E01 = __shfl_up(L01, 1);
    float E10 = __shfl_up(L10, 1), E11 = __shfl_up(L11, 1);
    float Ev0 = __shfl_up(Lv0, 1), Ev1 = __shfl_up(Lv1, 1);
    if (lane == 0) { E00 = 1.f; E01 = 0.f; E10 = 0.f; E11 = 1.f; Ev0 = 0.f; Ev1 = 0.f; }
    // C = E ∘ P : exclusive prefix from block start
    float C00 = E00 * P00 + E01 * P10;
    float C01 = E00 * P01 + E01 * P11;
    float C10 = E10 * P00 + E11 * P10;
    float C11 = E10 * P01 + E11 * P11;
    float Cv0 = fmaf(E00, Pv0, fmaf(E01, Pv1, Ev0));
    float Cv1 = fmaf(E10, Pv0, fmaf(E11, Pv1, Ev1));

    // block-start state (uniform scalar load) -> this chunk's initial state
    float s0 = S[b*2+0], s1 = S[b*2+1];
    float y1 = fmaf(C00, s0, fmaf(C01, s1, Cv0));
    float y2 = fmaf(C10, s0, fmaf(C11, s1, Cv1));

    // apply recurrence + fused FIR, write back into tile
    #pragma unroll
    for (int j = 0; j < CH; ++j) {
        float xs = tile[j][tid];
        float w = fmaf((float)j, scale, w0v);
        bool sel = w >= 1.0f;
        float wu = sel ? w - 1.0f : w;
        float l0a = sel ? k01 : k00, l0b = sel ? k02 : k01;
        float l1a = sel ? k11 : k10, l1b = sel ? k12 : k11;
        float b0a = sel ? k21 : k20, b0b = sel ? k22 : k21;
        float b1a = sel ? k31 : k30, b1b = sel ? k32 : k31;
        float b2a = sel ? k41 : k40, b2b = sel ? k42 : k41;
        float l0 = fmaf(wu, l0b - l0a, l0a);
        float l1 = fmaf(wu, l1b - l1a, l1a);
        float b0 = fmaf(wu, b0b - b0a, b0a);
        float b1 = fmaf(wu, b1b - b1a, b1a);
        float b2 = fmaf(wu, b2b - b2a, b2a);
        float a1 = stab2 * fast_tanh(l0);
        float a1a = fabsf(a1);
        float a2 = 0.5f * fmaf((2.0f - a1a) * stab, fast_tanh(l1), a1a);
        float y = fmaf(-a2, y2, xs);  y = fmaf(-a1, y1, y);
        tile[j][tid] = fmaf(b0, y, fmaf(b1, y1, b2 * y2));
        y2 = y1; y1 = y;
    }
    __syncthreads();

    // coalesced float4 store
    float4* out4 = (float4*)out + (size_t)b * (SPB / 4);
    #pragma unroll
    for (int i = 0; i < SPB / 4 / CPB; ++i) {
        int ii = tid + i * CPB;
        int idx = ii << 2;
        int cc = idx >> 4, qq = idx & 15;
        float4 v;
        v.x = tile[qq + 0][cc];
        v.y = tile[qq + 1][cc];
        v.z = tile[qq + 2][cc];
        v.w = tile[qq + 3][cc];
        out4[ii] = v;
    }
}

extern "C" void kernel_launch(void* const* d_in, const int* in_sizes, int n_in,
                              void* d_out, int out_size, void* d_ws, size_t ws_size,
                              hipStream_t stream) {
    const float* x  = (const float*)d_in[0];   // [32][262144]
    const float* cl = (const float*)d_in[1];   // [32][256][5]
    float* out = (float*)d_out;
    float* G = (float*)d_ws;                   // NB*6 floats (24 KB)
    float* S = G + (size_t)NB * 6;             // NB*2 floats (8 KB)

    hipLaunchKernelGGL(k_agg,     dim3(NB),  dim3(CPB), 0, stream, x, cl, G);
    hipLaunchKernelGGL(k_rowscan, dim3(BATCH), dim3(64), 0, stream, G, S);
    hipLaunchKernelGGL(k_apply,   dim3(NB),  dim3(CPB), 0, stream, x, cl, S, out);
}

// Round 7
// 42.679 us; speedup vs baseline: 5.9077x; 1.9458x over previous
//
#include <hip/hip_runtime.h>
#include <math.h>

#define BATCH 32
#define NSAMP 262144
#define NKNOT 256
#define EPSV  0.001f
#define CH    16                  // samples per chunk (per thread)
#define CPB   256                 // chunks per block (= threads/block)
#define SPB   (CH * CPB)          // 4096 samples per block
#define NCROW (NSAMP / CH)        // 16384 chunks per row
#define BPR   (NCROW / CPB)       // 64 blocks per row (= one wave in rowscan)
#define NB    (BATCH * BPR)       // 2048 blocks
#define NWAVE (CPB / 64)          // 4 waves per block
#define TSTRIDE (CPB + 2)         // 258 ≡ 2 (mod 32): every LDS phase ≤2-way = free

__device__ __forceinline__ float fast_tanh(float x) {
    // tanh(x) = 1 - 2/(exp(2x)+1); branch-free, ~1e-7 abs error
    float e = __expf(2.0f * x);
    float r = __builtin_amdgcn_rcpf(e + 1.0f);
    return fmaf(-2.0f, r, 1.0f);
}

// ---------------------------------------------------------------------------
// Kernel 1: per-block aggregate affine map G[b]  (no atomics; 48 KB output)
// ---------------------------------------------------------------------------
__global__ __launch_bounds__(256, 4) void k_agg(
    const float* __restrict__ x,
    const float* __restrict__ cl,     // [BATCH][NKNOT][5]
    float* __restrict__ G)            // [NB][6]
{
    __shared__ float tile[CH][TSTRIDE];   // 16.5 KB
    __shared__ float wag[NWAVE][6];
    const int tid = threadIdx.x;
    const int b = blockIdx.x;
    const int lane = tid & 63, wid = tid >> 6;

    // coalesced global load -> transposed LDS
    const float4* x4 = (const float4*)x + (size_t)b * (SPB / 4);
    #pragma unroll
    for (int i = 0; i < SPB / 4 / CPB; ++i) {   // 4 iters
        int ii = tid + i * CPB;
        float4 v = x4[ii];
        int idx = ii << 2;
        int cc = idx >> 4, qq = idx & 15;
        tile[qq + 0][cc] = v.x;
        tile[qq + 1][cc] = v.y;
        tile[qq + 2][cc] = v.z;
        tile[qq + 3][cc] = v.w;
    }

    // knot coefficients (channels 0,1) for this thread's chunk
    int chunk = b * CPB + tid;
    int r = chunk >> 14;                 // / NCROW (16384)
    int c = chunk & (NCROW - 1);
    const float scale = 255.0f / 262143.0f;
    float pos0 = (float)(c * CH) * scale;
    float fiA = floorf(pos0);
    int idxA = (int)fiA;
    float w0v = pos0 - fiA;
    const float* kb = cl + (size_t)r * NKNOT * 5;
    int i1 = min(idxA + 1, NKNOT - 1);
    int i2 = min(idxA + 2, NKNOT - 1);
    float k00 = kb[idxA*5+0], k01 = kb[i1*5+0], k02 = kb[i2*5+0];
    float k10 = kb[idxA*5+1], k11 = kb[i1*5+1], k12 = kb[i2*5+1];

    __syncthreads();

    // build per-chunk affine map  s_end = M s_start + v
    const float stab = 1.0f - EPSV, stab2 = 2.0f * stab;
    float p1 = 0.f, p2 = 0.f, A1 = 1.f, A2 = 0.f, B1 = 0.f, B2 = 1.f;
    #pragma unroll
    for (int j = 0; j < CH; ++j) {
        float xs = tile[j][tid];
        float w = fmaf((float)j, scale, w0v);
        bool sel = w >= 1.0f;
        float wu = sel ? w - 1.0f : w;
        float l0a = sel ? k01 : k00, l0b = sel ? k02 : k01;
        float l1a = sel ? k11 : k10, l1b = sel ? k12 : k11;
        float l0 = fmaf(wu, l0b - l0a, l0a);
        float l1 = fmaf(wu, l1b - l1a, l1a);
        float a1 = stab2 * fast_tanh(l0);
        float a1a = fabsf(a1);
        float a2 = 0.5f * fmaf((2.0f - a1a) * stab, fast_tanh(l1), a1a);
        float p  = fmaf(-a2, p2, xs);  p = fmaf(-a1, p1, p);
        float hA = fmaf(-a1, A1, -a2 * A2);
        float hB = fmaf(-a1, B1, -a2 * B2);
        p2 = p1; p1 = p;
        A2 = A1; A1 = hA;
        B2 = B1; B1 = hB;
    }
    float L00 = A1, L01 = B1, L10 = A2, L11 = B2, Lv0 = p1, Lv1 = p2;

    // wave-inclusive scan (compose later ∘ earlier)
    #pragma unroll
    for (int d = 1; d < 64; d <<= 1) {
        float o00 = __shfl_up(L00, d), o01 = __shfl_up(L01, d);
        float o10 = __shfl_up(L10, d), o11 = __shfl_up(L11, d);
        float ov0 = __shfl_up(Lv0, d), ov1 = __shfl_up(Lv1, d);
        if (lane >= d) {
            float n00 = L00 * o00 + L01 * o10;
            float n01 = L00 * o01 + L01 * o11;
            float n10 = L10 * o00 + L11 * o10;
            float n11 = L10 * o01 + L11 * o11;
            float nv0 = fmaf(L00, ov0, fmaf(L01, ov1, Lv0));
            float nv1 = fmaf(L10, ov0, fmaf(L11, ov1, Lv1));
            L00 = n00; L01 = n01; L10 = n10; L11 = n11; Lv0 = nv0; Lv1 = nv1;
        }
    }
    if (lane == 63) {
        wag[wid][0] = L00; wag[wid][1] = L01; wag[wid][2] = L10;
        wag[wid][3] = L11; wag[wid][4] = Lv0; wag[wid][5] = Lv1;
    }
    __syncthreads();

    // last thread composes wave aggregates -> block aggregate
    if (tid == CPB - 1) {
        float P00 = 1.f, P01 = 0.f, P10 = 0.f, P11 = 1.f, Pv0 = 0.f, Pv1 = 0.f;
        for (int w2 = 0; w2 < NWAVE - 1; ++w2) {
            float a00 = wag[w2][0], a01 = wag[w2][1], a10 = wag[w2][2];
            float a11 = wag[w2][3], av0 = wag[w2][4], av1 = wag[w2][5];
            float n00 = a00 * P00 + a01 * P10;
            float n01 = a00 * P01 + a01 * P11;
            float n10 = a10 * P00 + a11 * P10;
            float n11 = a10 * P01 + a11 * P11;
            float nv0 = fmaf(a00, Pv0, fmaf(a01, Pv1, av0));
            float nv1 = fmaf(a10, Pv0, fmaf(a11, Pv1, av1));
            P00 = n00; P01 = n01; P10 = n10; P11 = n11; Pv0 = nv0; Pv1 = nv1;
        }
        G[b*6+0] = L00 * P00 + L01 * P10;
        G[b*6+1] = L00 * P01 + L01 * P11;
        G[b*6+2] = L10 * P00 + L11 * P10;
        G[b*6+3] = L10 * P01 + L11 * P11;
        G[b*6+4] = fmaf(L00, Pv0, fmaf(L01, Pv1, Lv0));
        G[b*6+5] = fmaf(L10, Pv0, fmaf(L11, Pv1, Lv1));
    }
}

// ---------------------------------------------------------------------------
// Kernel 2: per-row scan of 64 block aggregates -> block-start states
// ---------------------------------------------------------------------------
__global__ __launch_bounds__(64) void k_rowscan(
    const float* __restrict__ G,      // [NB][6]
    float* __restrict__ S)            // [NB][2]
{
    int r = blockIdx.x;
    int lane = threadIdx.x;           // 64 = BPR
    int rowFirst = r * BPR;
    int k = rowFirst + lane;
    float A00 = G[k*6+0], A01 = G[k*6+1], A10 = G[k*6+2];
    float A11 = G[k*6+3], Av0 = G[k*6+4], Av1 = G[k*6+5];
    #pragma unroll
    for (int d = 1; d < BPR; d <<= 1) {
        float o00 = __shfl_up(A00, d), o01 = __shfl_up(A01, d);
        float o10 = __shfl_up(A10, d), o11 = __shfl_up(A11, d);
        float ov0 = __shfl_up(Av0, d), ov1 = __shfl_up(Av1, d);
        if (lane >= d) {
            float n00 = A00 * o00 + A01 * o10;
            float n01 = A00 * o01 + A01 * o11;
            float n10 = A10 * o00 + A11 * o10;
            float n11 = A10 * o01 + A11 * o11;
            float nv0 = fmaf(A00, ov0, fmaf(A01, ov1, Av0));
            float nv1 = fmaf(A10, ov0, fmaf(A11, ov1, Av1));
            A00 = n00; A01 = n01; A10 = n10; A11 = n11; Av0 = nv0; Av1 = nv1;
        }
    }
    // exclusive: state entering block (zero row-init -> vector part only)
    float e0 = __shfl_up(Av0, 1);
    float e1 = __shfl_up(Av1, 1);
    if (lane == 0) { e0 = 0.f; e1 = 0.f; }
    S[k*2 + 0] = e0;
    S[k*2 + 1] = e1;
}

// ---------------------------------------------------------------------------
// Kernel 3: rebuild + intra-block scan + apply recurrence + fused FIR
// ---------------------------------------------------------------------------
__global__ __launch_bounds__(256, 4) void k_apply(
    const float* __restrict__ x,
    const float* __restrict__ cl,
    const float* __restrict__ S,      // [NB][2]
    float* __restrict__ out)
{
    __shared__ float tile[CH][TSTRIDE];
    __shared__ float wag[NWAVE][6];
    const int tid = threadIdx.x;
    const int b = blockIdx.x;
    const int lane = tid & 63, wid = tid >> 6;

    const float4* x4 = (const float4*)x + (size_t)b * (SPB / 4);
    #pragma unroll
    for (int i = 0; i < SPB / 4 / CPB; ++i) {
        int ii = tid + i * CPB;
        float4 v = x4[ii];
        int idx = ii << 2;
        int cc = idx >> 4, qq = idx & 15;
        tile[qq + 0][cc] = v.x;
        tile[qq + 1][cc] = v.y;
        tile[qq + 2][cc] = v.z;
        tile[qq + 3][cc] = v.w;
    }

    int chunk = b * CPB + tid;
    int r = chunk >> 14;
    int c = chunk & (NCROW - 1);
    const float scale = 255.0f / 262143.0f;
    float pos0 = (float)(c * CH) * scale;
    float fiA = floorf(pos0);
    int idxA = (int)fiA;
    float w0v = pos0 - fiA;
    const float* kb = cl + (size_t)r * NKNOT * 5;
    int i1 = min(idxA + 1, NKNOT - 1);
    int i2 = min(idxA + 2, NKNOT - 1);
    float k00 = kb[idxA*5+0], k01 = kb[i1*5+0], k02 = kb[i2*5+0];
    float k10 = kb[idxA*5+1], k11 = kb[i1*5+1], k12 = kb[i2*5+1];
    float k20 = kb[idxA*5+2], k21 = kb[i1*5+2], k22 = kb[i2*5+2];
    float k30 = kb[idxA*5+3], k31 = kb[i1*5+3], k32 = kb[i2*5+3];
    float k40 = kb[idxA*5+4], k41 = kb[i1*5+4], k42 = kb[i2*5+4];

    __syncthreads();

    // rebuild per-chunk affine map (channels 0,1 only)
    const float stab = 1.0f - EPSV, stab2 = 2.0f * stab;
    float p1 = 0.f, p2 = 0.f, A1 = 1.f, A2 = 0.f, B1 = 0.f, B2 = 1.f;
    #pragma unroll
    for (int j = 0; j < CH; ++j) {
        float xs = tile[j][tid];
        float w = fmaf((float)j, scale, w0v);
        bool sel = w >= 1.0f;
        float wu = sel ? w - 1.0f : w;
        float l0a = sel ? k01 : k00, l0b = sel ? k02 : k01;
        float l1a = sel ? k11 : k10, l1b = sel ? k12 : k11;
        float l0 = fmaf(wu, l0b - l0a, l0a);
        float l1 = fmaf(wu, l1b - l1a, l1a);
        float a1 = stab2 * fast_tanh(l0);
        float a1a = fabsf(a1);
        float a2 = 0.5f * fmaf((2.0f - a1a) * stab, fast_tanh(l1), a1a);
        float p  = fmaf(-a2, p2, xs);  p = fmaf(-a1, p1, p);
        float hA = fmaf(-a1, A1, -a2 * A2);
        float hB = fmaf(-a1, B1, -a2 * B2);
        p2 = p1; p1 = p;
        A2 = A1; A1 = hA;
        B2 = B1; B1 = hB;
    }
    float L00 = A1, L01 = B1, L10 = A2, L11 = B2, Lv0 = p1, Lv1 = p2;

    // wave-inclusive scan
    #pragma unroll
    for (int d = 1; d < 64; d <<= 1) {
        float o00 = __shfl_up(L00, d), o01 = __shfl_up(L01, d);
        float o10 = __shfl_up(L10, d), o11 = __shfl_up(L11, d);
        float ov0 = __shfl_up(Lv0, d), ov1 = __shfl_up(Lv1, d);
        if (lane >= d) {
            float n00 = L00 * o00 + L01 * o10;
            float n01 = L00 * o01 + L01 * o11;
            float n10 = L10 * o00 + L11 * o10;
            float n11 = L10 * o01 + L11 * o11;
            float nv0 = fmaf(L00, ov0, fmaf(L01, ov1, Lv0));
            float nv1 = fmaf(L10, ov0, fmaf(L11, ov1, Lv1));
            L00 = n00; L01 = n01; L10 = n10; L11 = n11; Lv0 = nv0; Lv1 = nv1;
        }
    }
    if (lane == 63) {
        wag[wid][0] = L00; wag[wid][1] = L01; wag[wid][2] = L10;
        wag[wid][3] = L11; wag[wid][4] = Lv0; wag[wid][5] = Lv1;
    }
    __syncthreads();
    // P = compose of earlier waves
    float P00 = 1.f, P01 = 0.f, P10 = 0.f, P11 = 1.f, Pv0 = 0.f, Pv1 = 0.f;
    for (int w2 = 0; w2 < wid; ++w2) {
        float a00 = wag[w2][0], a01 = wag[w2][1], a10 = wag[w2][2];
        float a11 = wag[w2][3], av0 = wag[w2][4], av1 = wag[w2][5];
        float n00 = a00 * P00 + a01 * P10;
        float n01 = a00 * P01 + a01 * P11;
        float n10 = a10 * P00 + a11 * P10;
        float n11 = a10 * P01 + a11 * P11;
        float nv0 = fmaf(a00, Pv0, fmaf(a01, Pv1, av0));
        float nv1 = fmaf(a10, Pv0, fmaf(a11, Pv1, av1));
        P00 = n00; P01 = n01; P10 = n10; P11 = n11; Pv0 = nv0; Pv1 = nv1;
    }
    // in-wave exclusive E
    float E00 = __shfl_up(L00, 1), E01 = __shfl_up(L01, 1);
    float E10 = __shfl_up(L10, 1), E11 = __shfl_up(L11, 1);
    float Ev0 = __shfl_up(Lv0, 1), Ev1 = __shfl_up(Lv1, 1);
    if (lane == 0) { E00 = 1.f; E01 = 0.f; E10 = 0.f; E11 = 1.f; Ev0 = 0.f; Ev1 = 0.f; }
    // C = E ∘ P
    float C00 = E00 * P00 + E01 * P10;
    float C01 = E00 * P01 + E01 * P11;
    float C10 = E10 * P00 + E11 * P10;
    float C11 = E10 * P01 + E11 * P11;
    float Cv0 = fmaf(E00, Pv0, fmaf(E01, Pv1, Ev0));
    float Cv1 = fmaf(E10, Pv0, fmaf(E11, Pv1, Ev1));

    // block-start state -> this chunk's initial state
    float s0 = S[b*2+0], s1 = S[b*2+1];
    float y1 = fmaf(C00, s0, fmaf(C01, s1, Cv0));
    float y2 = fmaf(C10, s0, fmaf(C11, s1, Cv1));

    // apply recurrence + fused FIR, write back into tile
    #pragma unroll
    for (int j = 0; j < CH; ++j) {
        float xs = tile[j][tid];
        float w = fmaf((float)j, scale, w0v);
        bool sel = w >= 1.0f;
        float wu = sel ? w - 1.0f : w;
        float l0a = sel ? k01 : k00, l0b = sel ? k02 : k01;
        float l1a = sel ? k11 : k10, l1b = sel ? k12 : k11;
        float b0a = sel ? k21 : k20, b0b = sel ? k22 : k21;
        float b1a = sel ? k31 : k30, b1b = sel ? k32 : k31;
        float b2a = sel ? k41 : k40, b2b = sel ? k42 : k41;
        float l0 = fmaf(wu, l0b - l0a, l0a);
        float l1 = fmaf(wu, l1b - l1a, l1a);
        float b0 = fmaf(wu, b0b - b0a, b0a);
        float b1 = fmaf(wu, b1b - b1a, b1a);
        float b2 = fmaf(wu, b2b - b2a, b2a);
        float a1 = stab2 * fast_tanh(l0);
        float a1a = fabsf(a1);
        float a2 = 0.5f * fmaf((2.0f - a1a) * stab, fast_tanh(l1), a1a);
        float y = fmaf(-a2, y2, xs);  y = fmaf(-a1, y1, y);
        tile[j][tid] = fmaf(b0, y, fmaf(b1, y1, b2 * y2));
        y2 = y1; y1 = y;
    }
    __syncthreads();

    // coalesced float4 store
    float4* out4 = (float4*)out + (size_t)b * (SPB / 4);
    #pragma unroll
    for (int i = 0; i < SPB / 4 / CPB; ++i) {
        int ii = tid + i * CPB;
        int idx = ii << 2;
        int cc = idx >> 4, qq = idx & 15;
        float4 v;
        v.x = tile[qq + 0][cc];
        v.y = tile[qq + 1][cc];
        v.z = tile[qq + 2][cc];
        v.w = tile[qq + 3][cc];
        out4[ii] = v;
    }
}

extern "C" void kernel_launch(void* const* d_in, const int* in_sizes, int n_in,
                              void* d_out, int out_size, void* d_ws, size_t ws_size,
                              hipStream_t stream) {
    const float* x  = (const float*)d_in[0];   // [32][262144]
    const float* cl = (const float*)d_in[1];   // [32][256][5]
    float* out = (float*)d_out;
    float* G = (float*)d_ws;                   // NB*6 floats (48 KB)
    float* S = G + (size_t)NB * 6;             // NB*2 floats (16 KB)

    hipLaunchKernelGGL(k_agg,     dim3(NB),    dim3(CPB), 0, stream, x, cl, G);
    hipLaunchKernelGGL(k_rowscan, dim3(BATCH), dim3(64),  0, stream, G, S);
    hipLaunchKernelGGL(k_apply,   dim3(NB),    dim3(CPB), 0, stream, x, cl, S, out);
}